// Round 12
// baseline (600.609 us; speedup 1.0000x reference)
//
#include <hip/hip_runtime.h>
#include <hip/hip_bf16.h>

typedef __attribute__((ext_vector_type(8))) short s16x8;
typedef __attribute__((ext_vector_type(4))) float f32x4;

#define NEGC 1000000000000.0f

constexpr int B_ = 8, S_ = 512, H_ = 768;
constexpr int ENT = 12, ARG = 16;
constexpr int NC = 320;
constexpr int ROWS = B_ * S_;        // 4096
constexpr size_t OUT_ENT = (size_t)B_ * ENT * S_ * S_;

// Measurement round: idempotent reps sized to surface each kernel in the
// profiler top-5 (>137us). Revert next round.
constexpr int REP_PREP  = 150;
constexpr int REP_GEMM  = 25;
constexpr int REP_BCAST = 4;

static __device__ __forceinline__ unsigned short f2bf(float x) {
  return __builtin_bit_cast(unsigned short, __float2bfloat16(x));
}

typedef const __attribute__((address_space(1))) unsigned int gu32;
typedef __attribute__((address_space(3))) unsigned int lu32;
static __device__ __forceinline__ void glds16(const void* g, void* l) {
  __builtin_amdgcn_global_load_lds((gu32*)g, (lu32*)l, 16, 0, 0);
}

// ---------------------------------------------------------------------------
// Kernel 1: round-5 prep x REP_PREP.
// ---------------------------------------------------------------------------
__global__ __launch_bounds__(256) void k_prep(
    const float* __restrict__ X,
    const float* __restrict__ W1, const float* __restrict__ b1,
    const float* __restrict__ W2, const float* __restrict__ b2,
    const float* __restrict__ Wa1, const float* __restrict__ ba1,
    const float* __restrict__ Wa2, const float* __restrict__ ba2,
    __hip_bfloat16* __restrict__ Xb,
    __hip_bfloat16* __restrict__ Wt,
    float* __restrict__ bcat) {
  const int nx = ROWS * H_ / 4;
  for (int rep = 0; rep < REP_PREP; ++rep) {
    asm volatile("" ::: "memory");
    int idx = blockIdx.x * 256 + threadIdx.x;
    if (idx < nx) {
      float4 v = reinterpret_cast<const float4*>(X)[idx];
      ushort4 o;
      o.x = f2bf(v.x); o.y = f2bf(v.y); o.z = f2bf(v.z); o.w = f2bf(v.w);
      reinterpret_cast<ushort4*>(Xb)[idx] = o;
    } else {
      int i2 = idx - nx;
      if (i2 < NC * H_) {
        int n = i2 / H_;
        int k = i2 - n * H_;
        float v = 0.0f;
        if (n < 128)      v = W1[k * 128 + n];
        else if (n < 152) v = W2[k * 24 + (n - 128)];
        else if (n < 280) v = Wa1[k * 128 + (n - 152)];
        else if (n < 312) v = Wa2[k * 32 + (n - 280)];
        reinterpret_cast<unsigned short*>(Wt)[(size_t)n * H_ + k] = f2bf(v);
      } else {
        int i3 = i2 - NC * H_;
        if (i3 < NC) {
          int n = i3;
          float v = 0.0f;
          if (n < 128)      v = b1[n];
          else if (n < 152) v = b2[n - 128];
          else if (n < 280) v = ba1[n - 152];
          else if (n < 312) v = ba2[n - 280];
          bcat[n] = v;
        }
      }
    }
  }
}

// ---------------------------------------------------------------------------
// Kernel 2: round-9 LDS-staged GEMM x REP_GEMM.
// ---------------------------------------------------------------------------
__global__ __launch_bounds__(256) void k_gemm(
    const __hip_bfloat16* __restrict__ Xb,
    const __hip_bfloat16* __restrict__ Wt,
    const float* __restrict__ bcat,
    __hip_bfloat16* __restrict__ qwe, __hip_bfloat16* __restrict__ kwe,
    __hip_bfloat16* __restrict__ qwa, __hip_bfloat16* __restrict__ kwa,
    float* __restrict__ kbe, float* __restrict__ qbe,
    float* __restrict__ kba, float* __restrict__ qba) {
  __shared__ __hip_bfloat16 XA[2][32 * 64];
  __shared__ __hip_bfloat16 WA[2][64 * 64];
  const int tid  = threadIdx.x;
  const int lane = tid & 63;
  const int w    = tid >> 6;
  const int wm   = w & 1;
  const int wn   = w >> 1;
  const int rl   = lane & 15;
  const int rg   = lane >> 4;
  const int row0 = blockIdx.y * 32;
  const int col0 = blockIdx.x * 64;
  const int lr = lane >> 3, cc = lane & 7;
  const int scs = cc ^ lr;

  const short* Xs = reinterpret_cast<const short*>(Xb);
  const short* Ws = reinterpret_cast<const short*>(Wt);
  const size_t xsrc  = (size_t)(row0 + w * 8 + lr) * H_ + scs * 8;
  const size_t wsrc0 = (size_t)(col0 + w * 16 + lr) * H_ + scs * 8;
  const size_t wsrc1 = (size_t)(col0 + w * 16 + 8 + lr) * H_ + scs * 8;

  auto stage = [&](int t, int buf) {
    const size_t ko = (size_t)t * 64;
    glds16(Xs + xsrc + ko,  &XA[buf][(w * 8) * 64]);
    glds16(Ws + wsrc0 + ko, &WA[buf][(w * 16) * 64]);
    glds16(Ws + wsrc1 + ko, &WA[buf][(w * 16 + 8) * 64]);
  };

  for (int rep = 0; rep < REP_GEMM; ++rep) {
    asm volatile("" ::: "memory");
    f32x4 acc[2] = {};
    auto compute = [&](int buf) {
      const short* xl = reinterpret_cast<const short*>(XA[buf]);
      const short* wl = reinterpret_cast<const short*>(WA[buf]);
#pragma unroll
      for (int ks = 0; ks < 2; ++ks) {
        const int gc = ks * 4 + rg;
        const int mloc = wm * 16 + rl;
        s16x8 bfrag = *reinterpret_cast<const s16x8*>(xl + mloc * 64 + (gc ^ (rl & 7)) * 8);
#pragma unroll
        for (int ni = 0; ni < 2; ++ni) {
          const int nloc = wn * 32 + ni * 16 + rl;
          s16x8 afrag = *reinterpret_cast<const s16x8*>(wl + nloc * 64 + (gc ^ (rl & 7)) * 8);
          acc[ni] = __builtin_amdgcn_mfma_f32_16x16x32_bf16(afrag, bfrag, acc[ni], 0, 0, 0);
        }
      }
    };

    stage(0, 0);
    asm volatile("s_waitcnt vmcnt(0)" ::: "memory");
    __syncthreads();
#pragma unroll 2
    for (int t = 0; t < 12; ++t) {
      if (t < 11) stage(t + 1, (t + 1) & 1);
      compute(t & 1);
      asm volatile("s_waitcnt vmcnt(0)" ::: "memory");
      __syncthreads();
    }

    const int r = row0 + wm * 16 + rl;
    const int b = r >> 9, mm = r & 511;
#pragma unroll
    for (int ni = 0; ni < 2; ++ni) {
      const int nq = col0 + wn * 32 + ni * 16 + rg * 4;
      if (nq >= 312) continue;
      float4 bc = *reinterpret_cast<const float4*>(bcat + nq);
      float v0 = acc[ni][0] + bc.x;
      float v1 = acc[ni][1] + bc.y;
      float v2 = acc[ni][2] + bc.z;
      float v3 = acc[ni][3] + bc.w;
      if (nq < 128 || (nq >= 152 && nq < 280)) {
        const bool ent = nq < 128;
        const int p = (ent ? nq : nq - 152) >> 2;
        float inv = exp2f(-(float)p * 0.4152410118609203f);
        float s, c;
        sincosf((float)mm * inv, &s, &c);
        unsigned int qpk = (unsigned int)f2bf(v0 * c - v2 * s) |
                           ((unsigned int)f2bf(v2 * c + v0 * s) << 16);
        unsigned int kpk = (unsigned int)f2bf(v1 * c - v3 * s) |
                           ((unsigned int)f2bf(v3 * c + v1 * s) << 16);
        short* qd = reinterpret_cast<short*>(ent ? qwe : qwa);
        short* kd = reinterpret_cast<short*>(ent ? kwe : kwa);
        *reinterpret_cast<unsigned int*>(qd + (size_t)r * 64 + 2 * p) = qpk;
        *reinterpret_cast<unsigned int*>(kd + (size_t)r * 64 + 2 * p) = kpk;
      } else {
        const bool ent = nq < 152;
        const int base = ent ? 128 : 280;
        const int T = ent ? ENT : ARG;
        float* qb = ent ? qbe : qba;
        float* kb = ent ? kbe : kba;
        float vv[4] = {v0, v1, v2, v3};
#pragma unroll
        for (int q = 0; q < 4; ++q) {
          int e = nq - base + q;
          int t2 = e >> 1;
          float* dst = (e & 1) ? qb : kb;
          dst[((size_t)b * T + t2) * S_ + mm] = vv[q] * 0.5f;
        }
      }
    }
  }
}

// ---------------------------------------------------------------------------
// Kernel 3: round-9 combined-head bcast x REP_BCAST (best config, 61.2us).
// ---------------------------------------------------------------------------
__global__ __launch_bounds__(256) void k_bcast(
    const __hip_bfloat16* __restrict__ qwe, const __hip_bfloat16* __restrict__ kwe,
    const __hip_bfloat16* __restrict__ qwa, const __hip_bfloat16* __restrict__ kwa,
    const float* __restrict__ kbe, const float* __restrict__ qbe,
    const float* __restrict__ kba, const float* __restrict__ qba,
    const int* __restrict__ mask,
    float* __restrict__ out) {
  const int lane = threadIdx.x & 63;
  const int w = threadIdx.x >> 6;
  const int b = blockIdx.z;
  const int m0 = blockIdx.y * 64 + w * 16;
  const int n0 = blockIdx.x * 64;
  const int col = lane & 15;
  const int rg = lane >> 4;
  const int kseg = rg * 8;

  for (int rep = 0; rep < REP_BCAST; ++rep) {
    asm volatile("" ::: "memory");
    int mrow[4];
    float mqv[4], sqv[4];
#pragma unroll
    for (int j = 0; j < 4; ++j) {
      mrow[j] = m0 + rg * 4 + j;
      float mf = (float)mask[b * S_ + mrow[j]];
      mqv[j] = mf; sqv[j] = NEGC * (1.0f - mf);
    }
    int ncol[4];
    float mkv[4], skv[4];
#pragma unroll
    for (int f = 0; f < 4; ++f) {
      ncol[f] = n0 + 16 * f + col;
      float mf = (float)mask[b * S_ + ncol[f]];
      mkv[f] = mf; skv[f] = NEGC * (1.0f - mf);
    }
    float M[4][4], O[4][4];
#pragma unroll
    for (int f = 0; f < 4; ++f)
#pragma unroll
      for (int j = 0; j < 4; ++j) {
        M[f][j] = mqv[j] * mkv[f];
        O[f][j] = sqv[j] * mkv[f] + skv[f] + ((ncol[f] < mrow[j]) ? NEGC : 0.0f);
      }

    auto head = [&](const __hip_bfloat16* qw, const __hip_bfloat16* kw,
                    const float* qb, const float* kb, int T, size_t obase0) {
      const short* qs = reinterpret_cast<const short*>(qw);
      const short* ks = reinterpret_cast<const short*>(kw);
      f32x4 acc[4] = {};
#pragma unroll
      for (int kk = 0; kk < 64; kk += 32) {
        s16x8 a = *reinterpret_cast<const s16x8*>(
            qs + (size_t)(b * S_ + m0 + col) * 64 + kk + kseg);
#pragma unroll
        for (int f = 0; f < 4; ++f) {
          s16x8 bb = *reinterpret_cast<const s16x8*>(
              ks + (size_t)(b * S_ + n0 + 16 * f + col) * 64 + kk + kseg);
          acc[f] = __builtin_amdgcn_mfma_f32_16x16x32_bf16(a, bb, acc[f], 0, 0, 0);
        }
      }
      float accMO[4][4];
#pragma unroll
      for (int f = 0; f < 4; ++f)
#pragma unroll
        for (int j = 0; j < 4; ++j)
          accMO[f][j] = acc[f][j] * 0.125f * M[f][j] - O[f][j];

      for (int t = 0; t < T; ++t) {
        const float* qbp = qb + ((size_t)b * T + t) * S_;
        const float* kbp = kb + ((size_t)b * T + t) * S_;
        float qv[4];
#pragma unroll
        for (int j = 0; j < 4; ++j) qv[j] = qbp[mrow[j]];
        size_t obase = obase0 + (size_t)t * S_ * S_;
#pragma unroll
        for (int f = 0; f < 4; ++f) {
          float kv = kbp[ncol[f]];
#pragma unroll
          for (int j = 0; j < 4; ++j) {
            float v = fmaf(kv + qv[j], M[f][j], accMO[f][j]);
            out[obase + (size_t)mrow[j] * S_ + ncol[f]] = v;
          }
        }
      }
    };

    head(qwe, kwe, qbe, kbe, ENT, (size_t)b * ENT * S_ * S_);
    head(qwa, kwa, qba, kba, ARG, OUT_ENT + (size_t)b * ARG * S_ * S_);
  }
}

// ---------------------------------------------------------------------------
extern "C" void kernel_launch(void* const* d_in, const int* in_sizes, int n_in,
                              void* d_out, int out_size, void* d_ws, size_t ws_size,
                              hipStream_t stream) {
  (void)in_sizes; (void)n_in; (void)out_size; (void)ws_size;
  const float* X   = (const float*)d_in[0];
  const int* mask  = (const int*)d_in[1];
  const float* W1  = (const float*)d_in[2];
  const float* b1  = (const float*)d_in[3];
  const float* W2  = (const float*)d_in[4];
  const float* b2  = (const float*)d_in[5];
  const float* Wa1 = (const float*)d_in[6];
  const float* ba1 = (const float*)d_in[7];
  const float* Wa2 = (const float*)d_in[8];
  const float* ba2 = (const float*)d_in[9];
  float* out = (float*)d_out;

  char* ws = (char*)d_ws;
  size_t off = 0;
  auto walloc = [&](size_t bytes) -> void* {
    void* p = ws + off;
    off += (bytes + 255) & ~(size_t)255;
    return p;
  };
  __hip_bfloat16* Xb  = (__hip_bfloat16*)walloc((size_t)ROWS * H_ * 2);
  __hip_bfloat16* Wt  = (__hip_bfloat16*)walloc((size_t)NC * H_ * 2);
  float* bcat         = (float*)walloc((size_t)NC * 4);
  __hip_bfloat16* qwe = (__hip_bfloat16*)walloc((size_t)ROWS * 64 * 2);
  __hip_bfloat16* kwe = (__hip_bfloat16*)walloc((size_t)ROWS * 64 * 2);
  __hip_bfloat16* qwa = (__hip_bfloat16*)walloc((size_t)ROWS * 64 * 2);
  __hip_bfloat16* kwa = (__hip_bfloat16*)walloc((size_t)ROWS * 64 * 2);
  float* kbe = (float*)walloc((size_t)B_ * ENT * S_ * 4);
  float* qbe = (float*)walloc((size_t)B_ * ENT * S_ * 4);
  float* kba = (float*)walloc((size_t)B_ * ARG * S_ * 4);
  float* qba = (float*)walloc((size_t)B_ * ARG * S_ * 4);

  const int prep_tasks = ROWS * H_ / 4 + NC * H_ + NC;
  k_prep<<<dim3((prep_tasks + 255) / 256), dim3(256), 0, stream>>>(
      X, W1, b1, W2, b2, Wa1, ba1, Wa2, ba2, Xb, Wt, bcat);
  k_gemm<<<dim3(5, 128), dim3(256), 0, stream>>>(
      Xb, Wt, bcat, qwe, kwe, qwa, kwa, kbe, qbe, kba, qba);
  k_bcast<<<dim3(8, 8, 8), dim3(256), 0, stream>>>(
      qwe, kwe, qwa, kwa, kbe, qbe, kba, qba, mask, out);
}

// Round 13
// 68.453 us; speedup vs baseline: 8.7741x; 8.7741x over previous
//
#include <hip/hip_runtime.h>
#include <hip/hip_bf16.h>

typedef __attribute__((ext_vector_type(8))) short s16x8;
typedef __attribute__((ext_vector_type(4))) float f32x4;

#define NEGC 1000000000000.0f

constexpr int B_ = 8, S_ = 512, H_ = 768;
constexpr int ENT = 12, ARG = 16;
constexpr int NC = 320;
constexpr int ROWS = B_ * S_;        // 4096
constexpr size_t SS = (size_t)S_ * S_;
constexpr size_t OUT_ENT = (size_t)B_ * ENT * SS;

static __device__ __forceinline__ unsigned short f2bf(float x) {
  return __builtin_bit_cast(unsigned short, __float2bfloat16(x));
}
static __device__ __forceinline__ float bf2f(unsigned short u) {
  return __builtin_bit_cast(float, (unsigned int)u << 16);
}

typedef const __attribute__((address_space(1))) unsigned int gu32;
typedef __attribute__((address_space(3))) unsigned int lu32;
static __device__ __forceinline__ void glds16(const void* g, void* l) {
  __builtin_amdgcn_global_load_lds((gu32*)g, (lu32*)l, 16, 0, 0);
}

// ---------------------------------------------------------------------------
// Kernel 1: round-5 prep (exact).
// ---------------------------------------------------------------------------
__global__ __launch_bounds__(256) void k_prep(
    const float* __restrict__ X,
    const float* __restrict__ W1, const float* __restrict__ b1,
    const float* __restrict__ W2, const float* __restrict__ b2,
    const float* __restrict__ Wa1, const float* __restrict__ ba1,
    const float* __restrict__ Wa2, const float* __restrict__ ba2,
    __hip_bfloat16* __restrict__ Xb,
    __hip_bfloat16* __restrict__ Wt,
    float* __restrict__ bcat) {
  int idx = blockIdx.x * 256 + threadIdx.x;
  const int nx = ROWS * H_ / 4;
  if (idx < nx) {
    float4 v = reinterpret_cast<const float4*>(X)[idx];
    ushort4 o;
    o.x = f2bf(v.x); o.y = f2bf(v.y); o.z = f2bf(v.z); o.w = f2bf(v.w);
    reinterpret_cast<ushort4*>(Xb)[idx] = o;
    return;
  }
  idx -= nx;
  if (idx < NC * H_) {
    int n = idx / H_;
    int k = idx - n * H_;
    float v = 0.0f;
    if (n < 128)      v = W1[k * 128 + n];
    else if (n < 152) v = W2[k * 24 + (n - 128)];
    else if (n < 280) v = Wa1[k * 128 + (n - 152)];
    else if (n < 312) v = Wa2[k * 32 + (n - 280)];
    reinterpret_cast<unsigned short*>(Wt)[(size_t)n * H_ + k] = f2bf(v);
    return;
  }
  idx -= NC * H_;
  if (idx < NC) {
    int n = idx;
    float v = 0.0f;
    if (n < 128)      v = b1[n];
    else if (n < 152) v = b2[n - 128];
    else if (n < 280) v = ba1[n - 152];
    else if (n < 312) v = ba2[n - 280];
    bcat[n] = v;
  }
}

// ---------------------------------------------------------------------------
// Kernel 2: LDS-staged fused GEMM (exact round-9).
// ---------------------------------------------------------------------------
__global__ __launch_bounds__(256) void k_gemm(
    const __hip_bfloat16* __restrict__ Xb,
    const __hip_bfloat16* __restrict__ Wt,
    const float* __restrict__ bcat,
    __hip_bfloat16* __restrict__ qwe, __hip_bfloat16* __restrict__ kwe,
    __hip_bfloat16* __restrict__ qwa, __hip_bfloat16* __restrict__ kwa,
    float* __restrict__ kbe, float* __restrict__ qbe,
    float* __restrict__ kba, float* __restrict__ qba) {
  __shared__ __hip_bfloat16 XA[2][32 * 64];
  __shared__ __hip_bfloat16 WA[2][64 * 64];
  const int tid  = threadIdx.x;
  const int lane = tid & 63;
  const int w    = tid >> 6;
  const int wm   = w & 1;
  const int wn   = w >> 1;
  const int rl   = lane & 15;
  const int rg   = lane >> 4;
  const int row0 = blockIdx.y * 32;
  const int col0 = blockIdx.x * 64;
  const int lr = lane >> 3, cc = lane & 7;
  const int scs = cc ^ lr;

  const short* Xs = reinterpret_cast<const short*>(Xb);
  const short* Ws = reinterpret_cast<const short*>(Wt);
  const size_t xsrc  = (size_t)(row0 + w * 8 + lr) * H_ + scs * 8;
  const size_t wsrc0 = (size_t)(col0 + w * 16 + lr) * H_ + scs * 8;
  const size_t wsrc1 = (size_t)(col0 + w * 16 + 8 + lr) * H_ + scs * 8;

  auto stage = [&](int t, int buf) {
    const size_t ko = (size_t)t * 64;
    glds16(Xs + xsrc + ko,  &XA[buf][(w * 8) * 64]);
    glds16(Ws + wsrc0 + ko, &WA[buf][(w * 16) * 64]);
    glds16(Ws + wsrc1 + ko, &WA[buf][(w * 16 + 8) * 64]);
  };

  f32x4 acc[2] = {};
  auto compute = [&](int buf) {
    const short* xl = reinterpret_cast<const short*>(XA[buf]);
    const short* wl = reinterpret_cast<const short*>(WA[buf]);
#pragma unroll
    for (int ks = 0; ks < 2; ++ks) {
      const int gc = ks * 4 + rg;
      const int mloc = wm * 16 + rl;
      s16x8 bfrag = *reinterpret_cast<const s16x8*>(xl + mloc * 64 + (gc ^ (rl & 7)) * 8);
#pragma unroll
      for (int ni = 0; ni < 2; ++ni) {
        const int nloc = wn * 32 + ni * 16 + rl;
        s16x8 afrag = *reinterpret_cast<const s16x8*>(wl + nloc * 64 + (gc ^ (rl & 7)) * 8);
        acc[ni] = __builtin_amdgcn_mfma_f32_16x16x32_bf16(afrag, bfrag, acc[ni], 0, 0, 0);
      }
    }
  };

  stage(0, 0);
  asm volatile("s_waitcnt vmcnt(0)" ::: "memory");
  __syncthreads();
#pragma unroll 2
  for (int t = 0; t < 12; ++t) {
    if (t < 11) stage(t + 1, (t + 1) & 1);
    compute(t & 1);
    asm volatile("s_waitcnt vmcnt(0)" ::: "memory");
    __syncthreads();
  }

  const int r = row0 + wm * 16 + rl;
  const int b = r >> 9, mm = r & 511;
#pragma unroll
  for (int ni = 0; ni < 2; ++ni) {
    const int nq = col0 + wn * 32 + ni * 16 + rg * 4;
    if (nq >= 312) continue;
    float4 bc = *reinterpret_cast<const float4*>(bcat + nq);
    float v0 = acc[ni][0] + bc.x;
    float v1 = acc[ni][1] + bc.y;
    float v2 = acc[ni][2] + bc.z;
    float v3 = acc[ni][3] + bc.w;
    if (nq < 128 || (nq >= 152 && nq < 280)) {
      const bool ent = nq < 128;
      const int p = (ent ? nq : nq - 152) >> 2;
      float inv = exp2f(-(float)p * 0.4152410118609203f);
      float s, c;
      sincosf((float)mm * inv, &s, &c);
      unsigned int qpk = (unsigned int)f2bf(v0 * c - v2 * s) |
                         ((unsigned int)f2bf(v2 * c + v0 * s) << 16);
      unsigned int kpk = (unsigned int)f2bf(v1 * c - v3 * s) |
                         ((unsigned int)f2bf(v3 * c + v1 * s) << 16);
      short* qd = reinterpret_cast<short*>(ent ? qwe : qwa);
      short* kd = reinterpret_cast<short*>(ent ? kwe : kwa);
      *reinterpret_cast<unsigned int*>(qd + (size_t)r * 64 + 2 * p) = qpk;
      *reinterpret_cast<unsigned int*>(kd + (size_t)r * 64 + 2 * p) = kpk;
    } else {
      const bool ent = nq < 152;
      const int base = ent ? 128 : 280;
      const int T = ent ? ENT : ARG;
      float* qb = ent ? qbe : qba;
      float* kb = ent ? kbe : kba;
      float vv[4] = {v0, v1, v2, v3};
#pragma unroll
      for (int q = 0; q < 4; ++q) {
        int e = nq - base + q;
        int t = e >> 1;
        float* dst = (e & 1) ? qb : kb;
        dst[((size_t)b * T + t) * S_ + mm] = vv[q] * 0.5f;
      }
    }
  }
}

// ---------------------------------------------------------------------------
// Kernel 3a: qk scores -> bf16 buffer [head][b][m][n] (x0.125 folded in).
// Swapped MFMA (A=K, B=Q): quad along n -> one packed 8B store per fragment.
// Grid (8 n-tiles, 8 m-tiles, 8b x 2 heads) = 1024 blocks.
// ---------------------------------------------------------------------------
__global__ __launch_bounds__(256) void k_qk(
    const __hip_bfloat16* __restrict__ qwe, const __hip_bfloat16* __restrict__ kwe,
    const __hip_bfloat16* __restrict__ qwa, const __hip_bfloat16* __restrict__ kwa,
    unsigned short* __restrict__ qk) {
  const int lane = threadIdx.x & 63;
  const int w = threadIdx.x >> 6;
  const int hb = blockIdx.z;
  const int b = hb >> 1;
  const bool ent = (hb & 1) == 0;
  const int m0 = blockIdx.y * 64 + w * 16;
  const int n0 = blockIdx.x * 64;
  const int cl = lane & 15;
  const int rg = lane >> 4;
  const int kseg = rg * 8;

  const short* qs = reinterpret_cast<const short*>(ent ? qwe : qwa);
  const short* ks = reinterpret_cast<const short*>(ent ? kwe : kwa);

  f32x4 acc[4] = {};
#pragma unroll
  for (int kk = 0; kk < 64; kk += 32) {
    s16x8 bq = *reinterpret_cast<const s16x8*>(
        qs + (size_t)(b * S_ + m0 + cl) * 64 + kk + kseg);
#pragma unroll
    for (int f = 0; f < 4; ++f) {
      s16x8 ak = *reinterpret_cast<const s16x8*>(
          ks + (size_t)(b * S_ + n0 + f * 16 + cl) * 64 + kk + kseg);
      acc[f] = __builtin_amdgcn_mfma_f32_16x16x32_bf16(ak, bq, acc[f], 0, 0, 0);
    }
  }
  const size_t base = ((size_t)((ent ? 0 : 8) + b) * S_ + (m0 + cl)) * S_;
#pragma unroll
  for (int f = 0; f < 4; ++f) {
    ushort4 o;
    o.x = f2bf(acc[f][0] * 0.125f);
    o.y = f2bf(acc[f][1] * 0.125f);
    o.z = f2bf(acc[f][2] * 0.125f);
    o.w = f2bf(acc[f][3] * 0.125f);
    *reinterpret_cast<ushort4*>(qk + base + n0 + f * 16 + rg * 4) = o;
  }
}

// ---------------------------------------------------------------------------
// Kernel 3b: pure streaming writer. Block = (m-chunk 8, plane 28, b 8) =
// 1792 blocks; wave owns 16 consecutive rows (32KB contiguous writes).
// Per row: 2x 8B qk loads (L2), hoisted kv/mask vectors, 2x 1KB wave-stores.
// ---------------------------------------------------------------------------
__global__ __launch_bounds__(256) void k_stream(
    const unsigned short* __restrict__ qk,
    const float* __restrict__ kbe, const float* __restrict__ qbe,
    const float* __restrict__ kba, const float* __restrict__ qba,
    const int* __restrict__ mask,
    float* __restrict__ out) {
  const int lane = threadIdx.x & 63;
  const int w = threadIdx.x >> 6;
  const int t = blockIdx.y;       // 0..27
  const int b = blockIdx.z;
  const bool ent = t < ENT;
  const int tl = ent ? t : t - ENT;
  const int T = ent ? ENT : ARG;

  const float* qbp = (ent ? qbe : qba) + ((size_t)b * T + tl) * S_;
  const float* kbp = (ent ? kbe : kba) + ((size_t)b * T + tl) * S_;
  const size_t qkbase = ((size_t)((ent ? 0 : 8) + b) * S_) * S_;
  float* op = out + (ent ? ((size_t)b * ENT + tl) * SS
                         : OUT_ENT + ((size_t)b * ARG + tl) * SS);

  const int cA = lane * 4;
  const int cB = 256 + lane * 4;

  // hoisted per-plane/per-block values
  f32x4 kvA = *reinterpret_cast<const f32x4*>(kbp + cA);
  f32x4 kvB = *reinterpret_cast<const f32x4*>(kbp + cB);
  int4 miA = *reinterpret_cast<const int4*>(mask + b * S_ + cA);
  int4 miB = *reinterpret_cast<const int4*>(mask + b * S_ + cB);
  float mkA[4] = {(float)miA.x, (float)miA.y, (float)miA.z, (float)miA.w};
  float mkB[4] = {(float)miB.x, (float)miB.y, (float)miB.z, (float)miB.w};
  float skA[4], skB[4];
#pragma unroll
  for (int i = 0; i < 4; ++i) {
    skA[i] = NEGC * (1.0f - mkA[i]);
    skB[i] = NEGC * (1.0f - mkB[i]);
  }

  const int m0 = blockIdx.x * 64 + w * 16;
  for (int rr = 0; rr < 16; ++rr) {
    const int r = m0 + rr;
    const float mqf = (float)mask[b * S_ + r];
    const float sq = NEGC * (1.0f - mqf);
    const float qv = qbp[r];
    ushort4 ua = *reinterpret_cast<const ushort4*>(qk + qkbase + (size_t)r * S_ + cA);
    ushort4 ub = *reinterpret_cast<const ushort4*>(qk + qkbase + (size_t)r * S_ + cB);
    float qa[4] = {bf2f(ua.x), bf2f(ua.y), bf2f(ua.z), bf2f(ua.w)};
    float qb4[4] = {bf2f(ub.x), bf2f(ub.y), bf2f(ub.z), bf2f(ub.w)};
    f32x4 vA, vB;
#pragma unroll
    for (int i = 0; i < 4; ++i) {
      float MA = mqf * mkA[i];
      float OA = sq * mkA[i] + skA[i] + ((cA + i < r) ? NEGC : 0.0f);
      vA[i] = fmaf(qa[i] + kvA[i] + qv, MA, -OA);
      float MB = mqf * mkB[i];
      float OB = sq * mkB[i] + skB[i] + ((cB + i < r) ? NEGC : 0.0f);
      vB[i] = fmaf(qb4[i] + kvB[i] + qv, MB, -OB);
    }
    *reinterpret_cast<f32x4*>(op + (size_t)r * S_ + cA) = vA;
    *reinterpret_cast<f32x4*>(op + (size_t)r * S_ + cB) = vB;
  }
}

// ---------------------------------------------------------------------------
extern "C" void kernel_launch(void* const* d_in, const int* in_sizes, int n_in,
                              void* d_out, int out_size, void* d_ws, size_t ws_size,
                              hipStream_t stream) {
  (void)in_sizes; (void)n_in; (void)out_size; (void)ws_size;
  const float* X   = (const float*)d_in[0];
  const int* mask  = (const int*)d_in[1];
  const float* W1  = (const float*)d_in[2];
  const float* b1  = (const float*)d_in[3];
  const float* W2  = (const float*)d_in[4];
  const float* b2  = (const float*)d_in[5];
  const float* Wa1 = (const float*)d_in[6];
  const float* ba1 = (const float*)d_in[7];
  const float* Wa2 = (const float*)d_in[8];
  const float* ba2 = (const float*)d_in[9];
  float* out = (float*)d_out;

  char* ws = (char*)d_ws;
  size_t off = 0;
  auto walloc = [&](size_t bytes) -> void* {
    void* p = ws + off;
    off += (bytes + 255) & ~(size_t)255;
    return p;
  };
  __hip_bfloat16* Xb  = (__hip_bfloat16*)walloc((size_t)ROWS * H_ * 2);
  __hip_bfloat16* Wt  = (__hip_bfloat16*)walloc((size_t)NC * H_ * 2);
  float* bcat         = (float*)walloc((size_t)NC * 4);
  __hip_bfloat16* qwe = (__hip_bfloat16*)walloc((size_t)ROWS * 64 * 2);
  __hip_bfloat16* kwe = (__hip_bfloat16*)walloc((size_t)ROWS * 64 * 2);
  __hip_bfloat16* qwa = (__hip_bfloat16*)walloc((size_t)ROWS * 64 * 2);
  __hip_bfloat16* kwa = (__hip_bfloat16*)walloc((size_t)ROWS * 64 * 2);
  float* kbe = (float*)walloc((size_t)B_ * ENT * S_ * 4);
  float* qbe = (float*)walloc((size_t)B_ * ENT * S_ * 4);
  float* kba = (float*)walloc((size_t)B_ * ARG * S_ * 4);
  float* qba = (float*)walloc((size_t)B_ * ARG * S_ * 4);
  unsigned short* qk = (unsigned short*)walloc((size_t)2 * B_ * SS * 2);

  const int prep_tasks = ROWS * H_ / 4 + NC * H_ + NC;
  k_prep<<<dim3((prep_tasks + 255) / 256), dim3(256), 0, stream>>>(
      X, W1, b1, W2, b2, Wa1, ba1, Wa2, ba2, Xb, Wt, bcat);
  k_gemm<<<dim3(5, 128), dim3(256), 0, stream>>>(
      Xb, Wt, bcat, qwe, kwe, qwa, kwa, kbe, qbe, kba, qba);
  k_qk<<<dim3(8, 8, 16), dim3(256), 0, stream>>>(qwe, kwe, qwa, kwa, qk);
  k_stream<<<dim3(8, 28, 8), dim3(256), 0, stream>>>(
      qk, kbe, qbe, kba, qba, mask, out);
}

// Round 14
// 61.177 us; speedup vs baseline: 9.8176x; 1.1189x over previous
//
#include <hip/hip_runtime.h>
#include <hip/hip_bf16.h>

typedef __attribute__((ext_vector_type(8))) short s16x8;
typedef __attribute__((ext_vector_type(4))) float f32x4;

#define NEGC 1000000000000.0f

constexpr int B_ = 8, S_ = 512, H_ = 768;
constexpr int ENT = 12, ARG = 16;
constexpr int NC = 320;
constexpr int ROWS = B_ * S_;        // 4096
constexpr size_t OUT_ENT = (size_t)B_ * ENT * S_ * S_;

static __device__ __forceinline__ unsigned short f2bf(float x) {
  return __builtin_bit_cast(unsigned short, __float2bfloat16(x));
}

typedef const __attribute__((address_space(1))) unsigned int gu32;
typedef __attribute__((address_space(3))) unsigned int lu32;
static __device__ __forceinline__ void glds16(const void* g, void* l) {
  __builtin_amdgcn_global_load_lds((gu32*)g, (lu32*)l, 16, 0, 0);
}

// ---------------------------------------------------------------------------
// Kernel 1: round-5 prep (exact). Measured 1.76us (R12 reps).
// ---------------------------------------------------------------------------
__global__ __launch_bounds__(256) void k_prep(
    const float* __restrict__ X,
    const float* __restrict__ W1, const float* __restrict__ b1,
    const float* __restrict__ W2, const float* __restrict__ b2,
    const float* __restrict__ Wa1, const float* __restrict__ ba1,
    const float* __restrict__ Wa2, const float* __restrict__ ba2,
    __hip_bfloat16* __restrict__ Xb,
    __hip_bfloat16* __restrict__ Wt,
    float* __restrict__ bcat) {
  int idx = blockIdx.x * 256 + threadIdx.x;
  const int nx = ROWS * H_ / 4;
  if (idx < nx) {
    float4 v = reinterpret_cast<const float4*>(X)[idx];
    ushort4 o;
    o.x = f2bf(v.x); o.y = f2bf(v.y); o.z = f2bf(v.z); o.w = f2bf(v.w);
    reinterpret_cast<ushort4*>(Xb)[idx] = o;
    return;
  }
  idx -= nx;
  if (idx < NC * H_) {
    int n = idx / H_;
    int k = idx - n * H_;
    float v = 0.0f;
    if (n < 128)      v = W1[k * 128 + n];
    else if (n < 152) v = W2[k * 24 + (n - 128)];
    else if (n < 280) v = Wa1[k * 128 + (n - 152)];
    else if (n < 312) v = Wa2[k * 32 + (n - 280)];
    reinterpret_cast<unsigned short*>(Wt)[(size_t)n * H_ + k] = f2bf(v);
    return;
  }
  idx -= NC * H_;
  if (idx < NC) {
    int n = idx;
    float v = 0.0f;
    if (n < 128)      v = b1[n];
    else if (n < 152) v = b2[n - 128];
    else if (n < 280) v = ba1[n - 152];
    else if (n < 312) v = ba2[n - 280];
    bcat[n] = v;
  }
}

// ---------------------------------------------------------------------------
// Kernel 2: LDS-staged fused GEMM (exact round-9). ~6.7us measured by delta.
// ---------------------------------------------------------------------------
__global__ __launch_bounds__(256) void k_gemm(
    const __hip_bfloat16* __restrict__ Xb,
    const __hip_bfloat16* __restrict__ Wt,
    const float* __restrict__ bcat,
    __hip_bfloat16* __restrict__ qwe, __hip_bfloat16* __restrict__ kwe,
    __hip_bfloat16* __restrict__ qwa, __hip_bfloat16* __restrict__ kwa,
    float* __restrict__ kbe, float* __restrict__ qbe,
    float* __restrict__ kba, float* __restrict__ qba) {
  __shared__ __hip_bfloat16 XA[2][32 * 64];   // 8 KB
  __shared__ __hip_bfloat16 WA[2][64 * 64];   // 16 KB
  const int tid  = threadIdx.x;
  const int lane = tid & 63;
  const int w    = tid >> 6;
  const int wm   = w & 1;
  const int wn   = w >> 1;
  const int rl   = lane & 15;
  const int rg   = lane >> 4;
  const int row0 = blockIdx.y * 32;
  const int col0 = blockIdx.x * 64;
  const int lr = lane >> 3, cc = lane & 7;
  const int scs = cc ^ lr;

  const short* Xs = reinterpret_cast<const short*>(Xb);
  const short* Ws = reinterpret_cast<const short*>(Wt);
  const size_t xsrc  = (size_t)(row0 + w * 8 + lr) * H_ + scs * 8;
  const size_t wsrc0 = (size_t)(col0 + w * 16 + lr) * H_ + scs * 8;
  const size_t wsrc1 = (size_t)(col0 + w * 16 + 8 + lr) * H_ + scs * 8;

  auto stage = [&](int t, int buf) {
    const size_t ko = (size_t)t * 64;
    glds16(Xs + xsrc + ko,  &XA[buf][(w * 8) * 64]);
    glds16(Ws + wsrc0 + ko, &WA[buf][(w * 16) * 64]);
    glds16(Ws + wsrc1 + ko, &WA[buf][(w * 16 + 8) * 64]);
  };

  f32x4 acc[2] = {};
  auto compute = [&](int buf) {
    const short* xl = reinterpret_cast<const short*>(XA[buf]);
    const short* wl = reinterpret_cast<const short*>(WA[buf]);
#pragma unroll
    for (int ks = 0; ks < 2; ++ks) {
      const int gc = ks * 4 + rg;
      const int mloc = wm * 16 + rl;
      s16x8 bfrag = *reinterpret_cast<const s16x8*>(xl + mloc * 64 + (gc ^ (rl & 7)) * 8);
#pragma unroll
      for (int ni = 0; ni < 2; ++ni) {
        const int nloc = wn * 32 + ni * 16 + rl;
        s16x8 afrag = *reinterpret_cast<const s16x8*>(wl + nloc * 64 + (gc ^ (rl & 7)) * 8);
        acc[ni] = __builtin_amdgcn_mfma_f32_16x16x32_bf16(afrag, bfrag, acc[ni], 0, 0, 0);
      }
    }
  };

  stage(0, 0);
  asm volatile("s_waitcnt vmcnt(0)" ::: "memory");
  __syncthreads();
#pragma unroll 2
  for (int t = 0; t < 12; ++t) {
    if (t < 11) stage(t + 1, (t + 1) & 1);
    compute(t & 1);
    asm volatile("s_waitcnt vmcnt(0)" ::: "memory");
    __syncthreads();
  }

  const int r = row0 + wm * 16 + rl;
  const int b = r >> 9, mm = r & 511;
#pragma unroll
  for (int ni = 0; ni < 2; ++ni) {
    const int nq = col0 + wn * 32 + ni * 16 + rg * 4;
    if (nq >= 312) continue;
    float4 bc = *reinterpret_cast<const float4*>(bcat + nq);
    float v0 = acc[ni][0] + bc.x;
    float v1 = acc[ni][1] + bc.y;
    float v2 = acc[ni][2] + bc.z;
    float v3 = acc[ni][3] + bc.w;
    if (nq < 128 || (nq >= 152 && nq < 280)) {
      const bool ent = nq < 128;
      const int p = (ent ? nq : nq - 152) >> 2;
      float inv = exp2f(-(float)p * 0.4152410118609203f);
      float s, c;
      sincosf((float)mm * inv, &s, &c);
      unsigned int qpk = (unsigned int)f2bf(v0 * c - v2 * s) |
                         ((unsigned int)f2bf(v2 * c + v0 * s) << 16);
      unsigned int kpk = (unsigned int)f2bf(v1 * c - v3 * s) |
                         ((unsigned int)f2bf(v3 * c + v1 * s) << 16);
      short* qd = reinterpret_cast<short*>(ent ? qwe : qwa);
      short* kd = reinterpret_cast<short*>(ent ? kwe : kwa);
      *reinterpret_cast<unsigned int*>(qd + (size_t)r * 64 + 2 * p) = qpk;
      *reinterpret_cast<unsigned int*>(kd + (size_t)r * 64 + 2 * p) = kpk;
    } else {
      const bool ent = nq < 152;
      const int base = ent ? 128 : 280;
      const int T = ent ? ENT : ARG;
      float* qb = ent ? qbe : qba;
      float* kb = ent ? kbe : kba;
      float vv[4] = {v0, v1, v2, v3};
#pragma unroll
      for (int q = 0; q < 4; ++q) {
        int e = nq - base + q;
        int t = e >> 1;
        float* dst = (e & 1) ? qb : kb;
        dst[((size_t)b * T + t) * S_ + mm] = vv[q] * 0.5f;
      }
    }
  }
}

// ---------------------------------------------------------------------------
// Kernel 3: round-9 combined-head bcast (exact; best measured ~42us, at the
// ~5.6 TB/s compute+write store ceiling established by R3-R13 probes).
// ---------------------------------------------------------------------------
__global__ __launch_bounds__(256) void k_bcast(
    const __hip_bfloat16* __restrict__ qwe, const __hip_bfloat16* __restrict__ kwe,
    const __hip_bfloat16* __restrict__ qwa, const __hip_bfloat16* __restrict__ kwa,
    const float* __restrict__ kbe, const float* __restrict__ qbe,
    const float* __restrict__ kba, const float* __restrict__ qba,
    const int* __restrict__ mask,
    float* __restrict__ out) {
  const int lane = threadIdx.x & 63;
  const int w = threadIdx.x >> 6;
  const int b = blockIdx.z;
  const int m0 = blockIdx.y * 64 + w * 16;
  const int n0 = blockIdx.x * 64;
  const int col = lane & 15;
  const int rg = lane >> 4;
  const int kseg = rg * 8;

  int mrow[4];
  float mqv[4], sqv[4];
#pragma unroll
  for (int j = 0; j < 4; ++j) {
    mrow[j] = m0 + rg * 4 + j;
    float mf = (float)mask[b * S_ + mrow[j]];
    mqv[j] = mf; sqv[j] = NEGC * (1.0f - mf);
  }
  int ncol[4];
  float mkv[4], skv[4];
#pragma unroll
  for (int f = 0; f < 4; ++f) {
    ncol[f] = n0 + 16 * f + col;
    float mf = (float)mask[b * S_ + ncol[f]];
    mkv[f] = mf; skv[f] = NEGC * (1.0f - mf);
  }
  float M[4][4], O[4][4];
#pragma unroll
  for (int f = 0; f < 4; ++f)
#pragma unroll
    for (int j = 0; j < 4; ++j) {
      M[f][j] = mqv[j] * mkv[f];
      O[f][j] = sqv[j] * mkv[f] + skv[f] + ((ncol[f] < mrow[j]) ? NEGC : 0.0f);
    }

  auto head = [&](const __hip_bfloat16* qw, const __hip_bfloat16* kw,
                  const float* qb, const float* kb, int T, size_t obase0) {
    const short* qs = reinterpret_cast<const short*>(qw);
    const short* ks = reinterpret_cast<const short*>(kw);
    f32x4 acc[4] = {};
#pragma unroll
    for (int kk = 0; kk < 64; kk += 32) {
      s16x8 a = *reinterpret_cast<const s16x8*>(
          qs + (size_t)(b * S_ + m0 + col) * 64 + kk + kseg);
#pragma unroll
      for (int f = 0; f < 4; ++f) {
        s16x8 bb = *reinterpret_cast<const s16x8*>(
            ks + (size_t)(b * S_ + n0 + 16 * f + col) * 64 + kk + kseg);
        acc[f] = __builtin_amdgcn_mfma_f32_16x16x32_bf16(a, bb, acc[f], 0, 0, 0);
      }
    }
    float accMO[4][4];
#pragma unroll
    for (int f = 0; f < 4; ++f)
#pragma unroll
      for (int j = 0; j < 4; ++j)
        accMO[f][j] = acc[f][j] * 0.125f * M[f][j] - O[f][j];

    for (int t = 0; t < T; ++t) {
      const float* qbp = qb + ((size_t)b * T + t) * S_;
      const float* kbp = kb + ((size_t)b * T + t) * S_;
      float qv[4];
#pragma unroll
      for (int j = 0; j < 4; ++j) qv[j] = qbp[mrow[j]];
      size_t obase = obase0 + (size_t)t * S_ * S_;
#pragma unroll
      for (int f = 0; f < 4; ++f) {
        float kv = kbp[ncol[f]];
#pragma unroll
        for (int j = 0; j < 4; ++j) {
          float v = fmaf(kv + qv[j], M[f][j], accMO[f][j]);
          out[obase + (size_t)mrow[j] * S_ + ncol[f]] = v;
        }
      }
    }
  };

  head(qwe, kwe, qbe, kbe, ENT, (size_t)b * ENT * S_ * S_);
  head(qwa, kwa, qba, kba, ARG, OUT_ENT + (size_t)b * ARG * S_ * S_);
}

// ---------------------------------------------------------------------------
extern "C" void kernel_launch(void* const* d_in, const int* in_sizes, int n_in,
                              void* d_out, int out_size, void* d_ws, size_t ws_size,
                              hipStream_t stream) {
  (void)in_sizes; (void)n_in; (void)out_size; (void)ws_size;
  const float* X   = (const float*)d_in[0];
  const int* mask  = (const int*)d_in[1];
  const float* W1  = (const float*)d_in[2];
  const float* b1  = (const float*)d_in[3];
  const float* W2  = (const float*)d_in[4];
  const float* b2  = (const float*)d_in[5];
  const float* Wa1 = (const float*)d_in[6];
  const float* ba1 = (const float*)d_in[7];
  const float* Wa2 = (const float*)d_in[8];
  const float* ba2 = (const float*)d_in[9];
  float* out = (float*)d_out;

  char* ws = (char*)d_ws;
  size_t off = 0;
  auto walloc = [&](size_t bytes) -> void* {
    void* p = ws + off;
    off += (bytes + 255) & ~(size_t)255;
    return p;
  };
  __hip_bfloat16* Xb  = (__hip_bfloat16*)walloc((size_t)ROWS * H_ * 2);
  __hip_bfloat16* Wt  = (__hip_bfloat16*)walloc((size_t)NC * H_ * 2);
  float* bcat         = (float*)walloc((size_t)NC * 4);
  __hip_bfloat16* qwe = (__hip_bfloat16*)walloc((size_t)ROWS * 64 * 2);
  __hip_bfloat16* kwe = (__hip_bfloat16*)walloc((size_t)ROWS * 64 * 2);
  __hip_bfloat16* qwa = (__hip_bfloat16*)walloc((size_t)ROWS * 64 * 2);
  __hip_bfloat16* kwa = (__hip_bfloat16*)walloc((size_t)ROWS * 64 * 2);
  float* kbe = (float*)walloc((size_t)B_ * ENT * S_ * 4);
  float* qbe = (float*)walloc((size_t)B_ * ENT * S_ * 4);
  float* kba = (float*)walloc((size_t)B_ * ARG * S_ * 4);
  float* qba = (float*)walloc((size_t)B_ * ARG * S_ * 4);

  const int prep_tasks = ROWS * H_ / 4 + NC * H_ + NC;
  k_prep<<<dim3((prep_tasks + 255) / 256), dim3(256), 0, stream>>>(
      X, W1, b1, W2, b2, Wa1, ba1, Wa2, ba2, Xb, Wt, bcat);
  k_gemm<<<dim3(5, 128), dim3(256), 0, stream>>>(
      Xb, Wt, bcat, qwe, kwe, qwa, kwa, kbe, qbe, kba, qba);
  k_bcast<<<dim3(8, 8, 8), dim3(256), 0, stream>>>(
      qwe, kwe, qwa, kwa, kbe, qbe, kba, qba, mask, out);
}